// Round 4
// baseline (115.239 us; speedup 1.0000x reference)
//
#include <hip/hip_runtime.h>
#include <hip/hip_bf16.h>
#include <math.h>

#define D_DIM 512
#define TB    128          // symmetric tile (R18)

typedef int i32x4 __attribute__((ext_vector_type(4)));
typedef unsigned long long u64;

// ---- helpers ---------------------------------------------------------------

__device__ inline void async16(unsigned char* lds, const unsigned char* g) {
    __builtin_amdgcn_global_load_lds(
        (const __attribute__((address_space(1))) void*)g,
        (__attribute__((address_space(3))) void*)lds,
        16, 0, 0);
}

// ---- kernel 1: row L2-normalize -> int8 (x127), init best/acc/cnt ----------

__global__ __launch_bounds__(256) void normalize_rows(
        const float* __restrict__ in, unsigned char* __restrict__ xb,
        float* __restrict__ inv_norm, u64* __restrict__ best,
        float* __restrict__ acc, int* __restrict__ cnt) {
    const int row  = blockIdx.x * 4 + (threadIdx.x >> 6);
    const int lane = threadIdx.x & 63;
    if (blockIdx.x == 0 && threadIdx.x == 0) { acc[0] = 0.f; cnt[0] = 0; }
    const float4* rp = (const float4*)(in + (size_t)row * D_DIM) + lane * 2;
    float4 a = rp[0], b = rp[1];
    float s = a.x*a.x + a.y*a.y + a.z*a.z + a.w*a.w
            + b.x*b.x + b.y*b.y + b.z*b.z + b.w*b.w;
    #pragma unroll
    for (int m = 1; m <= 32; m <<= 1) s += __shfl_xor(s, m, 64);
    float inv = 1.0f / fmaxf(sqrtf(s), 1e-8f);
    if (lane == 0) {
        inv_norm[row] = inv;
        best[row] = 0ull;   // below any real packed key
    }
    float sc = inv * 127.0f;   // int8 symmetric quant; |x_norm|<=1 -> no clamp
    int q0 = __float2int_rn(a.x*sc), q1 = __float2int_rn(a.y*sc);
    int q2 = __float2int_rn(a.z*sc), q3 = __float2int_rn(a.w*sc);
    int q4 = __float2int_rn(b.x*sc), q5 = __float2int_rn(b.y*sc);
    int q6 = __float2int_rn(b.z*sc), q7 = __float2int_rn(b.w*sc);
    int lo = (q0 & 255) | ((q1 & 255) << 8) | ((q2 & 255) << 16) | ((q3 & 255) << 24);
    int hi = (q4 & 255) | ((q5 & 255) << 8) | ((q6 & 255) << 16) | ((q7 & 255) << 24);
    ((int2*)(xb + (size_t)row * D_DIM))[lane] = make_int2(lo, hi);
}

// ---- kernel 2: 128x128-tile int8 GEMM + argmax (R18) -----------------------
// R17 post-mortem: throughput floors (LDS 3us, MFMA 9us) are far below the
// measured 38us; warm time == 3 generations x T_b: 1056 tiles over 512
// block-slots (2 blocks/CU) = 2.06 gens -> last 32 blocks start at 2*T_b,
// makespan 3*12.7 = 38us (69% util). The limiter is schedule QUANTIZATION,
// not latency/BW.
// R18: halve the quantum. Symmetric 128x128 tiles (2080 of them), 256
// threads / 4 waves (same 64x64 wave-tile, 64-reg acc), single-buffered
// BK=128 (32KB LDS, merge aliased) -> 4 blocks/CU = 1024 slots; makespan
// ~3 x 6.5-7.5us. Also: barriers sync 4 waves not 8, 8 barriers/block
// (R11-proven drain pattern beat counted-vmcnt dbuf in R16), and 4
// independent blocks/CU overlap stage/compute across blocks (m114).
// Swizzle (both sides, rule #21): LDS[r][s16] = G[r][s16 ^ (r&7)] via
// pre-swizzled source slot ((t&7)^((t>>3)&7)); read pos (ks*4+quad)^(qr&7)
// -> 2 lanes/bank, zero conflicts (R11/R17-verified pattern).
// u32 tile-local keys (R17): |i8 dot| <= 512*127^2 < 2^23, local idx < 128
// -> key = (dot+0x800000)<<8 | (255-lidx); v_max_u32 + 32-bit shfl.
// NOTE (R12-R14): do NOT fuse the neighbor gather into this kernel.

__global__ __launch_bounds__(256, 4) void gemm_argmax(
        const unsigned char* __restrict__ X, u64* __restrict__ best) {
    __shared__ unsigned char smem[32768];
    unsigned char* As = smem;                            // 128 rows x 128B
    unsigned char* Bs = smem + 16384;                    // 128 rows x 128B
    unsigned int* rmerge = (unsigned int*)smem;          // [128][2] 1KB alias
    unsigned int* cmerge = (unsigned int*)(smem + 1024); // [128][2] 1KB alias

    // triangular decode: l -> (bi, bj), bi <= bj, l = bj(bj+1)/2 + bi
    int l = blockIdx.x;
    int bj = (int)((sqrtf(8.0f * (float)l + 1.0f) - 1.0f) * 0.5f);
    while ((bj + 1) * (bj + 2) / 2 <= l) ++bj;
    while (bj * (bj + 1) / 2 > l) --bj;
    int bi = l - bj * (bj + 1) / 2;
    const int m0 = bi * TB;
    const int n0 = bj * TB;

    const int t    = threadIdx.x;
    const int lane = t & 63;
    const int w    = t >> 6;            // 0..3
    const int wm   = w >> 1;            // row half (64 rows)
    const int wn   = w & 1;             // col half (64 cols)
    const int qr   = lane & 15;
    const int quad = lane >> 4;

    // staging: 8 async16/thread per K-step. row = j*32 + (t>>3), slot = t&7,
    // source slot pre-swizzled by row&7 ( = (t>>3)&7 since 32 = 0 mod 8 ).
    const int srcsl = ((t & 7) ^ ((t >> 3) & 7)) * 16;
    const unsigned char* gA = X + (size_t)(m0 + (t >> 3)) * D_DIM + srcsl;
    const unsigned char* gB = X + (size_t)(n0 + (t >> 3)) * D_DIM + srcsl;

    #define STAGE(k0)                                                   \
        do {                                                            \
            _Pragma("unroll")                                           \
            for (int j = 0; j < 4; j++)                                 \
                async16(As + j * 4096 + t * 16,                         \
                        gA + (size_t)(j * 32) * D_DIM + (k0));          \
            _Pragma("unroll")                                           \
            for (int j = 0; j < 4; j++)                                 \
                async16(Bs + j * 4096 + t * 16,                         \
                        gB + (size_t)(j * 32) * D_DIM + (k0));          \
        } while (0)

    i32x4 accm[4][4];
    #pragma unroll
    for (int mi = 0; mi < 4; mi++)
        #pragma unroll
        for (int ni = 0; ni < 4; ni++)
            accm[mi][ni] = (i32x4){0, 0, 0, 0};

    #pragma unroll
    for (int kt = 0; kt < 4; kt++) {
        STAGE(kt * 128);
        __syncthreads();                 // vmcnt(0)+lgkmcnt drain + barrier
        #pragma unroll
        for (int ks = 0; ks < 2; ks++) {
            // pos uniform across mi/ni: row&7 == qr&7 (16-row stride)
            const int pos = ((ks * 4 + quad) ^ (qr & 7)) * 16;
            const unsigned char* pA = As + (wm * 64 + qr) * 128 + pos;
            const unsigned char* pB = Bs + (wn * 64 + qr) * 128 + pos;
            i32x4 av[4], bv[4];
            #pragma unroll
            for (int mi = 0; mi < 4; mi++)
                av[mi] = *(const i32x4*)(pA + mi * 2048);
            #pragma unroll
            for (int ni = 0; ni < 4; ni++)
                bv[ni] = *(const i32x4*)(pB + ni * 2048);
            #pragma unroll
            for (int mi = 0; mi < 4; mi++)
                #pragma unroll
                for (int ni = 0; ni < 4; ni++)
                    accm[mi][ni] = __builtin_amdgcn_mfma_i32_16x16x64_i8(
                        av[mi], bv[ni], accm[mi][ni], 0, 0, 0);
        }
        __syncthreads();                 // all reads done; safe to overwrite
    }
    #undef STAGE

    // ---- epilogue: u32 tile-local keys ------------------------------------
    const int colg_base = n0 + wn * 64 + qr;          // + ni*16

    // row-side argmax over this wave's 64 cols (diag masked)
    #pragma unroll
    for (int mi = 0; mi < 4; mi++) {
        #pragma unroll
        for (int r = 0; r < 4; r++) {
            const int rowl = wm * 64 + mi * 16 + quad * 4 + r;
            const int rowg = m0 + rowl;
            unsigned key = 0u;
            #pragma unroll
            for (int ni = 0; ni < 4; ni++) {
                const int colg = colg_base + ni * 16;
                const unsigned lcol = (unsigned)(wn * 64 + ni * 16 + qr);
                unsigned k = (((unsigned)accm[mi][ni][r] + 0x800000u) << 8)
                           | (255u - lcol);
                k = (colg == rowg) ? 0u : k;
                key = key > k ? key : k;
            }
            #pragma unroll
            for (int m = 1; m <= 8; m <<= 1) {
                unsigned o = (unsigned)__shfl_xor((int)key, m, 64);
                key = key > o ? key : o;
            }
            if (qr == 0) rmerge[rowl * 2 + wn] = key;
        }
    }

    // col-side argmax (symmetry; diag masked here too)
    #pragma unroll
    for (int ni = 0; ni < 4; ni++) {
        const int colg = colg_base + ni * 16;
        unsigned key = 0u;
        #pragma unroll
        for (int mi = 0; mi < 4; mi++) {
            #pragma unroll
            for (int r = 0; r < 4; r++) {
                const unsigned lrow = (unsigned)(wm * 64 + mi * 16 + quad * 4 + r);
                const int rowg = m0 + (int)lrow;
                unsigned k = (((unsigned)accm[mi][ni][r] + 0x800000u) << 8)
                           | (255u - lrow);
                k = (rowg == colg) ? 0u : k;
                key = key > k ? key : k;
            }
        }
        unsigned o = (unsigned)__shfl_xor((int)key, 16, 64);
        key = key > o ? key : o;
        o = (unsigned)__shfl_xor((int)key, 32, 64);
        key = key > o ? key : o;
        if (quad == 0) cmerge[(wn * 64 + ni * 16 + qr) * 2 + wm] = key;
    }
    __syncthreads();

    if (t < TB) {
        unsigned a0 = rmerge[t * 2], a1 = rmerge[t * 2 + 1];
        unsigned k = a0 > a1 ? a0 : a1;
        unsigned bd32 = (k >> 8) + 0x7F800000u;
        unsigned colg = (unsigned)(n0 + 255) - (k & 255u);
        u64 kk = ((u64)bd32 << 32) | (u64)(0xFFFFFFFFu - colg);
        atomicMax(&best[m0 + t], kk);
    } else {
        const int tt = t - TB;
        unsigned c0 = cmerge[tt * 2], c1 = cmerge[tt * 2 + 1];
        unsigned k = c0 > c1 ? c0 : c1;
        unsigned bd32 = (k >> 8) + 0x7F800000u;
        unsigned rowg = (unsigned)(m0 + 255) - (k & 255u);
        u64 kk = ((u64)bd32 << 32) | (u64)(0xFFFFFFFFu - rowg);
        atomicMax(&best[n0 + tt], kk);
    }
}

// ---- kernel 3: exact fp32 distance + fused mean (256-block cheap ticket) ---

__global__ __launch_bounds__(256) void neighbor_reduce(
        const float* __restrict__ in, const float* __restrict__ inv_norm,
        const u64* __restrict__ best, float* __restrict__ acc,
        int* __restrict__ cnt, float* __restrict__ out, int B) {
    const int wave = threadIdx.x >> 6;
    const int lane = threadIdx.x & 63;
    float lsum = 0.f;
    #pragma unroll
    for (int rr = 0; rr < 8; rr++) {
        const int row = blockIdx.x * 32 + wave * 8 + rr;
        u64 k   = best[row];
        int nbr = (int)(0xFFFFFFFFu - (unsigned)(k & 0xFFFFFFFFull));
        float ir  = inv_norm[row];
        float inb = inv_norm[nbr];
        const float4* rp = (const float4*)(in + (size_t)row * D_DIM) + lane * 2;
        const float4* np = (const float4*)(in + (size_t)nbr * D_DIM) + lane * 2;
        float4 r0 = rp[0], r1 = rp[1], q0 = np[0], q1 = np[1];
        float d0 = r0.x*ir - q0.x*inb + 1e-8f, d1 = r0.y*ir - q0.y*inb + 1e-8f;
        float d2 = r0.z*ir - q0.z*inb + 1e-8f, d3 = r0.w*ir - q0.w*inb + 1e-8f;
        float d4 = r1.x*ir - q1.x*inb + 1e-8f, d5 = r1.y*ir - q1.y*inb + 1e-8f;
        float d6 = r1.z*ir - q1.z*inb + 1e-8f, d7 = r1.w*ir - q1.w*inb + 1e-8f;
        float s = d0*d0 + d1*d1 + d2*d2 + d3*d3 + d4*d4 + d5*d5 + d6*d6 + d7*d7;
        #pragma unroll
        for (int m = 1; m <= 32; m <<= 1) s += __shfl_xor(s, m, 64);
        if (lane == 0) lsum += logf(sqrtf(s) + 1e-8f);
    }
    __shared__ float sb[4];
    if (lane == 0) sb[wave] = lsum;
    __syncthreads();
    if (threadIdx.x == 0) {
        float partial = sb[0] + sb[1] + sb[2] + sb[3];
        atomicAdd(acc, partial);
        __threadfence();
        int done = atomicAdd(cnt, 1);
        if (done == gridDim.x - 1) {
            __threadfence();
            float tot = atomicAdd(acc, 0.0f);   // device-scope read of final sum
            out[0] = -tot / (float)B;
        }
    }
}

// ---- launch ----------------------------------------------------------------

extern "C" void kernel_launch(void* const* d_in, const int* in_sizes, int n_in,
                              void* d_out, int out_size, void* d_ws, size_t ws_size,
                              hipStream_t stream) {
    const float* in = (const float*)d_in[0];
    const int B = in_sizes[0] / D_DIM;          // 8192
    const int nb = B / TB;                      // 64 bands
    const int nblk = nb * (nb + 1) / 2;         // 2080 triangular tiles

    char* w = (char*)d_ws;
    unsigned char* xb = (unsigned char*)w;                     // B*D int8
    float* invn = (float*)(w + (size_t)B * D_DIM);
    u64*   best = (u64*)(w + (size_t)B * D_DIM + (size_t)B * 4);
    float* acc  = (float*)(w + (size_t)B * D_DIM + (size_t)B * 4 + (size_t)B * 8);
    int*   cnt  = (int*)(acc + 1);
    float* out  = (float*)d_out;

    normalize_rows<<<B / 4, 256, 0, stream>>>(in, xb, invn, best, acc, cnt);
    gemm_argmax<<<nblk, 256, 0, stream>>>(xb, best);
    neighbor_reduce<<<B / 32, 256, 0, stream>>>(in, invn, best, acc, cnt, out, B);
}

// Round 5
// 112.915 us; speedup vs baseline: 1.0206x; 1.0206x over previous
//
#include <hip/hip_runtime.h>
#include <hip/hip_bf16.h>
#include <math.h>

#define D_DIM 512
#define TM    128
#define TN    256

typedef int i32x4 __attribute__((ext_vector_type(4)));
typedef unsigned long long u64;

// ---- helpers ---------------------------------------------------------------

__device__ inline void async16(unsigned char* lds, const unsigned char* g) {
    __builtin_amdgcn_global_load_lds(
        (const __attribute__((address_space(1))) void*)g,
        (__attribute__((address_space(3))) void*)lds,
        16, 0, 0);
}

// ---- kernel 1: row L2-normalize -> int8 (x127), init best/acc/cnt ----------

__global__ __launch_bounds__(256) void normalize_rows(
        const float* __restrict__ in, unsigned char* __restrict__ xb,
        float* __restrict__ inv_norm, u64* __restrict__ best,
        float* __restrict__ acc, int* __restrict__ cnt) {
    const int row  = blockIdx.x * 4 + (threadIdx.x >> 6);
    const int lane = threadIdx.x & 63;
    if (blockIdx.x == 0 && threadIdx.x == 0) { acc[0] = 0.f; cnt[0] = 0; }
    const float4* rp = (const float4*)(in + (size_t)row * D_DIM) + lane * 2;
    float4 a = rp[0], b = rp[1];
    float s = a.x*a.x + a.y*a.y + a.z*a.z + a.w*a.w
            + b.x*b.x + b.y*b.y + b.z*b.z + b.w*b.w;
    #pragma unroll
    for (int m = 1; m <= 32; m <<= 1) s += __shfl_xor(s, m, 64);
    float inv = 1.0f / fmaxf(sqrtf(s), 1e-8f);
    if (lane == 0) {
        inv_norm[row] = inv;
        best[row] = 0ull;   // below any real packed key
    }
    float sc = inv * 127.0f;   // int8 symmetric quant; |x_norm|<=1 -> no clamp
    int q0 = __float2int_rn(a.x*sc), q1 = __float2int_rn(a.y*sc);
    int q2 = __float2int_rn(a.z*sc), q3 = __float2int_rn(a.w*sc);
    int q4 = __float2int_rn(b.x*sc), q5 = __float2int_rn(b.y*sc);
    int q6 = __float2int_rn(b.z*sc), q7 = __float2int_rn(b.w*sc);
    int lo = (q0 & 255) | ((q1 & 255) << 8) | ((q2 & 255) << 16) | ((q3 & 255) << 24);
    int hi = (q4 & 255) | ((q5 & 255) << 8) | ((q6 & 255) << 16) | ((q7 & 255) << 24);
    ((int2*)(xb + (size_t)row * D_DIM))[lane] = make_int2(lo, hi);
}

// ---- kernel 2: 128x256-tile int8 GEMM + argmax (R19) -----------------------
// R18 post-mortem: tile-size changes can't beat the ceil(tiles/slots)
// generation quantization (pigeonhole), and depth-0 drain re-exposed stage
// latency. Cross-round evidence: depth-0 (R11/R18) worst per-work, depth-1
// (R16/R17) marginal -> the serial term per K-step is stage L2 service
// (~900-1900cy) vs a 1-step shadow (~1000cy).
// R19 = R17 + TRIPLE-buffered LDS, depth-2 prefetch: issue k-tile s+2 while
// computing s; steady-state vmcnt(6) should wait ~0. LDS 3x24KB + 4KB merge
// = 77824 <= 80KB -> still 2 blocks/CU (512 thr, 16 waves/CU). Everything
// else identical to R17 (8 waves of 64x64, u32 tile-local keys, both-sides
// swizzle, padded-triangular grid with bi%8 == l%8 XCD banding).
// Buffer hazard check: step t8 issues into buf (t8+2)%3, whose previous
// k-tile (t8-1) was consumed at step t8-1 which ended with s_barrier.
// NOTE (R12-R14): do NOT fuse the neighbor gather into this kernel.

__global__ __launch_bounds__(512, 4) void gemm_argmax(
        const unsigned char* __restrict__ X, u64* __restrict__ best) {
    __shared__ unsigned char As[3][8192];    // 3 x (128 rows x 64B)
    __shared__ unsigned char Bs[3][16384];   // 3 x (256 rows x 64B)
    __shared__ unsigned int rmerge[TM * 4];  // 2 KB (separate, no alias)
    __shared__ unsigned int cmerge[TN * 2];  // 2 KB

    // decode padded id: col-group q (4 cols of width-256), per-col cnt 8(q+1)
    int l = blockIdx.x;
    int q = (int)(sqrtf((float)l / 16.0f + 0.25f) - 0.5f);
    while (16 * (q + 1) * (q + 2) <= l) ++q;
    while (16 * q * (q + 1) > l) --q;
    int rrem = l - 16 * q * (q + 1);
    int cw   = 8 * (q + 1);
    int c    = rrem / cw;
    int bi   = rrem - c * cw;           // row tile (128-wide), bi%8 == l%8
    int bj   = 4 * q + c;               // col tile (256-wide)
    if (bi > 2 * bj + 1) return;        // padding / fully-below-diagonal
    const int m0 = bi * TM;
    const int n0 = bj * TN;

    const int t    = threadIdx.x;
    const int lane = t & 63;
    const int w    = t >> 6;            // 0..7
    const int wm   = w >> 2;            // row half   (64 rows)
    const int wn   = w & 3;             // col quarter (64 cols)
    const int qr   = lane & 15;
    const int quad = lane >> 4;

    // staging source: row t>>2, pre-swizzled k-slot
    const int srcsl = ((t & 3) ^ ((t >> 3) & 3)) * 16;
    const unsigned char* gA  = X + (size_t)(m0 + (t >> 2)) * D_DIM + srcsl;
    const unsigned char* gB  = X + (size_t)(n0 + (t >> 2)) * D_DIM + srcsl;
    const unsigned char* gB2 = gB + (size_t)128 * D_DIM;

    #define STAGE(buf, k0)                                        \
        do {                                                      \
            async16(&As[buf][t * 16], gA + (k0));                 \
            async16(&Bs[buf][t * 16], gB + (k0));                 \
            async16(&Bs[buf][8192 + t * 16], gB2 + (k0));         \
        } while (0)

    i32x4 accm[4][4];
    #pragma unroll
    for (int mi = 0; mi < 4; mi++)
        #pragma unroll
        for (int ni = 0; ni < 4; ni++)
            accm[mi][ni] = (i32x4){0, 0, 0, 0};

    const int rdsl = (quad ^ ((qr >> 1) & 3)) * 16;   // read-side swizzle

    STAGE(0, 0);
    STAGE(1, 64);
    #pragma unroll
    for (int t8 = 0; t8 < 8; t8++) {
        const int cur = t8 % 3;                    // compile-time (unrolled)
        if (t8 < 6) {
            STAGE((t8 + 2) % 3, (t8 + 2) * 64);    // depth-2 prefetch
            asm volatile("s_waitcnt vmcnt(6)" ::: "memory");  // k-tile t8 landed
        } else if (t8 == 6) {
            asm volatile("s_waitcnt vmcnt(3)" ::: "memory");
        } else {
            asm volatile("s_waitcnt vmcnt(0)" ::: "memory");
        }
        __builtin_amdgcn_s_barrier();

        i32x4 av[4], bv[4];
        const unsigned char* pA = &As[cur][(wm * 64 + qr) * 64 + rdsl];
        const unsigned char* pB = &Bs[cur][(wn * 64 + qr) * 64 + rdsl];
        #pragma unroll
        for (int mi = 0; mi < 4; mi++)
            av[mi] = *(const i32x4*)(pA + mi * 1024);
        #pragma unroll
        for (int ni = 0; ni < 4; ni++)
            bv[ni] = *(const i32x4*)(pB + ni * 1024);
        #pragma unroll
        for (int mi = 0; mi < 4; mi++)
            #pragma unroll
            for (int ni = 0; ni < 4; ni++)
                accm[mi][ni] = __builtin_amdgcn_mfma_i32_16x16x64_i8(
                    av[mi], bv[ni], accm[mi][ni], 0, 0, 0);

        asm volatile("" ::: "memory");   // keep frag reads above this barrier
        __builtin_amdgcn_s_barrier();    // reads consumed; safe to overwrite
    }
    #undef STAGE

    // ---- epilogue: u32 tile-local keys ------------------------------------
    const int colg_base = n0 + wn * 64 + qr;          // + ni*16

    // row-side argmax over this wave's 64 cols (diag masked)
    #pragma unroll
    for (int mi = 0; mi < 4; mi++) {
        #pragma unroll
        for (int r = 0; r < 4; r++) {
            const int rowl = wm * 64 + mi * 16 + quad * 4 + r;
            const int rowg = m0 + rowl;
            unsigned key = 0u;
            #pragma unroll
            for (int ni = 0; ni < 4; ni++) {
                const int colg = colg_base + ni * 16;
                const unsigned lcol = (unsigned)(wn * 64 + ni * 16 + qr);
                unsigned k = (((unsigned)accm[mi][ni][r] + 0x800000u) << 8)
                           | (255u - lcol);
                k = (colg == rowg) ? 0u : k;
                key = key > k ? key : k;
            }
            #pragma unroll
            for (int m = 1; m <= 8; m <<= 1) {
                unsigned o = (unsigned)__shfl_xor((int)key, m, 64);
                key = key > o ? key : o;
            }
            if (qr == 0) rmerge[rowl * 4 + wn] = key;
        }
    }

    // col-side argmax (symmetry; diag masked here too)
    #pragma unroll
    for (int ni = 0; ni < 4; ni++) {
        const int colg = colg_base + ni * 16;
        unsigned key = 0u;
        #pragma unroll
        for (int mi = 0; mi < 4; mi++) {
            #pragma unroll
            for (int r = 0; r < 4; r++) {
                const unsigned lrow = (unsigned)(wm * 64 + mi * 16 + quad * 4 + r);
                const int rowg = m0 + (int)lrow;
                unsigned k = (((unsigned)accm[mi][ni][r] + 0x800000u) << 8)
                           | (255u - lrow);
                k = (rowg == colg) ? 0u : k;
                key = key > k ? key : k;
            }
        }
        unsigned o = (unsigned)__shfl_xor((int)key, 16, 64);
        key = key > o ? key : o;
        o = (unsigned)__shfl_xor((int)key, 32, 64);
        key = key > o ? key : o;
        if (quad == 0) cmerge[(wn * 64 + ni * 16 + qr) * 2 + wm] = key;
    }
    __syncthreads();

    if (t < TM) {
        unsigned a0 = rmerge[t * 4], a1 = rmerge[t * 4 + 1];
        unsigned a2 = rmerge[t * 4 + 2], a3 = rmerge[t * 4 + 3];
        unsigned k01 = a0 > a1 ? a0 : a1;
        unsigned k23 = a2 > a3 ? a2 : a3;
        unsigned k = k01 > k23 ? k01 : k23;
        // expand to global u64 key: bd32 = dot + 2^31, tie-break smaller col
        unsigned bd32 = (k >> 8) + 0x7F800000u;
        unsigned colg = (unsigned)(n0 + 255) - (k & 255u);
        u64 kk = ((u64)bd32 << 32) | (u64)(0xFFFFFFFFu - colg);
        atomicMax(&best[m0 + t], kk);
    }
    if (t < TN) {
        unsigned c0 = cmerge[t * 2], c1 = cmerge[t * 2 + 1];
        unsigned k = c0 > c1 ? c0 : c1;
        unsigned bd32 = (k >> 8) + 0x7F800000u;
        unsigned rowg = (unsigned)(m0 + 255) - (k & 255u);
        u64 kk = ((u64)bd32 << 32) | (u64)(0xFFFFFFFFu - rowg);
        atomicMax(&best[n0 + t], kk);
    }
}

// ---- kernel 3: exact fp32 distance + fused mean (256-block cheap ticket) ---

__global__ __launch_bounds__(256) void neighbor_reduce(
        const float* __restrict__ in, const float* __restrict__ inv_norm,
        const u64* __restrict__ best, float* __restrict__ acc,
        int* __restrict__ cnt, float* __restrict__ out, int B) {
    const int wave = threadIdx.x >> 6;
    const int lane = threadIdx.x & 63;
    float lsum = 0.f;
    #pragma unroll
    for (int rr = 0; rr < 8; rr++) {
        const int row = blockIdx.x * 32 + wave * 8 + rr;
        u64 k   = best[row];
        int nbr = (int)(0xFFFFFFFFu - (unsigned)(k & 0xFFFFFFFFull));
        float ir  = inv_norm[row];
        float inb = inv_norm[nbr];
        const float4* rp = (const float4*)(in + (size_t)row * D_DIM) + lane * 2;
        const float4* np = (const float4*)(in + (size_t)nbr * D_DIM) + lane * 2;
        float4 r0 = rp[0], r1 = rp[1], q0 = np[0], q1 = np[1];
        float d0 = r0.x*ir - q0.x*inb + 1e-8f, d1 = r0.y*ir - q0.y*inb + 1e-8f;
        float d2 = r0.z*ir - q0.z*inb + 1e-8f, d3 = r0.w*ir - q0.w*inb + 1e-8f;
        float d4 = r1.x*ir - q1.x*inb + 1e-8f, d5 = r1.y*ir - q1.y*inb + 1e-8f;
        float d6 = r1.z*ir - q1.z*inb + 1e-8f, d7 = r1.w*ir - q1.w*inb + 1e-8f;
        float s = d0*d0 + d1*d1 + d2*d2 + d3*d3 + d4*d4 + d5*d5 + d6*d6 + d7*d7;
        #pragma unroll
        for (int m = 1; m <= 32; m <<= 1) s += __shfl_xor(s, m, 64);
        if (lane == 0) lsum += logf(sqrtf(s) + 1e-8f);
    }
    __shared__ float sb[4];
    if (lane == 0) sb[wave] = lsum;
    __syncthreads();
    if (threadIdx.x == 0) {
        float partial = sb[0] + sb[1] + sb[2] + sb[3];
        atomicAdd(acc, partial);
        __threadfence();
        int done = atomicAdd(cnt, 1);
        if (done == gridDim.x - 1) {
            __threadfence();
            float tot = atomicAdd(acc, 0.0f);   // device-scope read of final sum
            out[0] = -tot / (float)B;
        }
    }
}

// ---- launch ----------------------------------------------------------------

extern "C" void kernel_launch(void* const* d_in, const int* in_sizes, int n_in,
                              void* d_out, int out_size, void* d_ws, size_t ws_size,
                              hipStream_t stream) {
    const float* in = (const float*)d_in[0];
    const int B = in_sizes[0] / D_DIM;          // 8192
    const int nblk = 16 * 8 * 9;                // 1152 padded tiles (8 col-groups)

    char* w = (char*)d_ws;
    unsigned char* xb = (unsigned char*)w;                     // B*D int8
    float* invn = (float*)(w + (size_t)B * D_DIM);
    u64*   best = (u64*)(w + (size_t)B * D_DIM + (size_t)B * 4);
    float* acc  = (float*)(w + (size_t)B * D_DIM + (size_t)B * 4 + (size_t)B * 8);
    int*   cnt  = (int*)(acc + 1);
    float* out  = (float*)d_out;

    normalize_rows<<<B / 4, 256, 0, stream>>>(in, xb, invn, best, acc, cnt);
    gemm_argmax<<<nblk, 512, 0, stream>>>(xb, best);
    neighbor_reduce<<<B / 32, 256, 0, stream>>>(in, invn, best, acc, cnt, out, B);
}

// Round 6
// 108.283 us; speedup vs baseline: 1.0642x; 1.0428x over previous
//
#include <hip/hip_runtime.h>
#include <hip/hip_bf16.h>
#include <math.h>

#define D_DIM 512
#define TM    128
#define TN    256

typedef int i32x4 __attribute__((ext_vector_type(4)));
typedef unsigned long long u64;

// ---- helpers ---------------------------------------------------------------

__device__ inline void async16(unsigned char* lds, const unsigned char* g) {
    __builtin_amdgcn_global_load_lds(
        (const __attribute__((address_space(1))) void*)g,
        (__attribute__((address_space(3))) void*)lds,
        16, 0, 0);
}

// ---- kernel 1: row L2-normalize -> int8 (x127), init best/acc/cnt ----------

__global__ __launch_bounds__(256) void normalize_rows(
        const float* __restrict__ in, unsigned char* __restrict__ xb,
        float* __restrict__ inv_norm, u64* __restrict__ best,
        float* __restrict__ acc, int* __restrict__ cnt) {
    const int row  = blockIdx.x * 4 + (threadIdx.x >> 6);
    const int lane = threadIdx.x & 63;
    if (blockIdx.x == 0 && threadIdx.x == 0) { acc[0] = 0.f; cnt[0] = 0; }
    const float4* rp = (const float4*)(in + (size_t)row * D_DIM) + lane * 2;
    float4 a = rp[0], b = rp[1];
    float s = a.x*a.x + a.y*a.y + a.z*a.z + a.w*a.w
            + b.x*b.x + b.y*b.y + b.z*b.z + b.w*b.w;
    #pragma unroll
    for (int m = 1; m <= 32; m <<= 1) s += __shfl_xor(s, m, 64);
    float inv = 1.0f / fmaxf(sqrtf(s), 1e-8f);
    if (lane == 0) {
        inv_norm[row] = inv;
        best[row] = 0ull;   // below any real packed key
    }
    float sc = inv * 127.0f;   // int8 symmetric quant; |x_norm|<=1 -> no clamp
    int q0 = __float2int_rn(a.x*sc), q1 = __float2int_rn(a.y*sc);
    int q2 = __float2int_rn(a.z*sc), q3 = __float2int_rn(a.w*sc);
    int q4 = __float2int_rn(b.x*sc), q5 = __float2int_rn(b.y*sc);
    int q6 = __float2int_rn(b.z*sc), q7 = __float2int_rn(b.w*sc);
    int lo = (q0 & 255) | ((q1 & 255) << 8) | ((q2 & 255) << 16) | ((q3 & 255) << 24);
    int hi = (q4 & 255) | ((q5 & 255) << 8) | ((q6 & 255) << 16) | ((q7 & 255) << 24);
    ((int2*)(xb + (size_t)row * D_DIM))[lane] = make_int2(lo, hi);
}

// ---- kernel 2: 128x256-tile int8 GEMM + argmax (R20) -----------------------
// R19 post-mortem: pipeline depth 0/1/2 and occupancy 2x all null at
// MfmaUtil ~13.5% -> the wall is stage BANDWIDTH below L2. Old bi-banding
// put all 32 B-panels on every XCD (64 blocks x 128KB = 8MB >> 4MB L2), so
// the 207MB of stage traffic was served by Infinity Cache at ~4.5TB/s
// ~= 45us -- matching every LDS variant (38-50us).
// R20 = R17 kernel verbatim, NEW tile->block mapping only:
//   XCD x (= blockIdx%8, per T1 lore) owns columns bj in {x, 31-x, x+8,
//   23-x} -> exactly 132 tiles/XCD (balanced). Within an XCD, tiles are
//   ordered column-major (bi ascending), so the ~64 concurrent blocks
//   share 1-2 B-panels (<=256KB, L2-resident): 138MB of B traffic -> L2
//   hits. A streams 67MB from LLC. Decode = 3 compares, no sqrt.
// Coverage: column bj needs bi <= 2bj+1 (128-row bands vs 256-col bands);
// r<c pairs covered exactly once, r>c via col-side symmetry, diag masked.
// NOTE (R12-R14): do NOT fuse the neighbor gather into this kernel.

__global__ __launch_bounds__(512, 4) void gemm_argmax(
        const unsigned char* __restrict__ X, u64* __restrict__ best) {
    __shared__ unsigned char smem[49152];
    unsigned char* As0 = smem;                       // [2][8192]  A: 128x64B
    unsigned char* Bs0 = smem + 16384;               // [2][16384] B: 256x64B
    unsigned int* rmerge = (unsigned int*)smem;          // [128][4] 2KB (alias)
    unsigned int* cmerge = (unsigned int*)(smem + 2048); // [256][2] 2KB (alias)

    // column-affinity decode: xcd = l%8 owns bj in {x, 31-x, x+8, 23-x},
    // concatenated lengths L0=2x+2, L1=64-2x, L2=2x+18, L3=48-2x (sum 132).
    {
    }
    const int l    = blockIdx.x;
    const int x    = l & 7;
    const int rank = l >> 3;            // 0..143 (12 pad per XCD)
    if (rank >= 132) return;
    int bi, bj;
    const int L0 = 2 * x + 2;
    if (rank < L0)                 { bj = x;      bi = rank; }
    else if (rank < 66)            { bj = 31 - x; bi = rank - L0; }
    else if (rank < 2 * x + 84)    { bj = x + 8;  bi = rank - 66; }
    else                           { bj = 23 - x; bi = rank - (2 * x + 84); }
    const int m0 = bi * TM;
    const int n0 = bj * TN;

    const int t    = threadIdx.x;
    const int lane = t & 63;
    const int w    = t >> 6;            // 0..7
    const int wm   = w >> 2;            // row half   (64 rows)
    const int wn   = w & 3;             // col quarter (64 cols)
    const int qr   = lane & 15;
    const int quad = lane >> 4;

    // staging source: row t>>2, pre-swizzled k-slot
    const int srcsl = ((t & 3) ^ ((t >> 3) & 3)) * 16;
    const unsigned char* gA  = X + (size_t)(m0 + (t >> 2)) * D_DIM + srcsl;
    const unsigned char* gB  = X + (size_t)(n0 + (t >> 2)) * D_DIM + srcsl;
    const unsigned char* gB2 = gB + (size_t)128 * D_DIM;

    #define STAGE(buf, k0)                                        \
        do {                                                      \
            async16(As0 + (buf) * 8192 + t * 16, gA + (k0));      \
            async16(Bs0 + (buf) * 16384 + t * 16, gB + (k0));     \
            async16(Bs0 + (buf) * 16384 + 8192 + t * 16, gB2 + (k0)); \
        } while (0)

    i32x4 accm[4][4];
    #pragma unroll
    for (int mi = 0; mi < 4; mi++)
        #pragma unroll
        for (int ni = 0; ni < 4; ni++)
            accm[mi][ni] = (i32x4){0, 0, 0, 0};

    const int rdsl = (quad ^ ((qr >> 1) & 3)) * 16;   // read-side swizzle

    STAGE(0, 0);
    #pragma unroll
    for (int t8 = 0; t8 < 8; t8++) {
        const int cur = t8 & 1;
        if (t8 < 7) {
            STAGE(cur ^ 1, (t8 + 1) * 64);
            asm volatile("s_waitcnt vmcnt(3)" ::: "memory");  // buf[cur] landed
        } else {
            asm volatile("s_waitcnt vmcnt(0)" ::: "memory");
        }
        __builtin_amdgcn_s_barrier();

        i32x4 av[4], bv[4];
        const unsigned char* pA = As0 + cur * 8192  + (wm * 64 + qr) * 64 + rdsl;
        const unsigned char* pB = Bs0 + cur * 16384 + (wn * 64 + qr) * 64 + rdsl;
        #pragma unroll
        for (int mi = 0; mi < 4; mi++)
            av[mi] = *(const i32x4*)(pA + mi * 1024);
        #pragma unroll
        for (int ni = 0; ni < 4; ni++)
            bv[ni] = *(const i32x4*)(pB + ni * 1024);
        #pragma unroll
        for (int mi = 0; mi < 4; mi++)
            #pragma unroll
            for (int ni = 0; ni < 4; ni++)
                accm[mi][ni] = __builtin_amdgcn_mfma_i32_16x16x64_i8(
                    av[mi], bv[ni], accm[mi][ni], 0, 0, 0);

        asm volatile("" ::: "memory");   // keep frag reads above this barrier
        __builtin_amdgcn_s_barrier();    // reads consumed; safe to overwrite
    }
    #undef STAGE

    // ---- epilogue: u32 tile-local keys ------------------------------------
    const int colg_base = n0 + wn * 64 + qr;          // + ni*16

    // row-side argmax over this wave's 64 cols (diag masked)
    #pragma unroll
    for (int mi = 0; mi < 4; mi++) {
        #pragma unroll
        for (int r = 0; r < 4; r++) {
            const int rowl = wm * 64 + mi * 16 + quad * 4 + r;
            const int rowg = m0 + rowl;
            unsigned key = 0u;
            #pragma unroll
            for (int ni = 0; ni < 4; ni++) {
                const int colg = colg_base + ni * 16;
                const unsigned lcol = (unsigned)(wn * 64 + ni * 16 + qr);
                unsigned k = (((unsigned)accm[mi][ni][r] + 0x800000u) << 8)
                           | (255u - lcol);
                k = (colg == rowg) ? 0u : k;
                key = key > k ? key : k;
            }
            #pragma unroll
            for (int m = 1; m <= 8; m <<= 1) {
                unsigned o = (unsigned)__shfl_xor((int)key, m, 64);
                key = key > o ? key : o;
            }
            if (qr == 0) rmerge[rowl * 4 + wn] = key;
        }
    }

    // col-side argmax (symmetry; diag masked here too)
    #pragma unroll
    for (int ni = 0; ni < 4; ni++) {
        const int colg = colg_base + ni * 16;
        unsigned key = 0u;
        #pragma unroll
        for (int mi = 0; mi < 4; mi++) {
            #pragma unroll
            for (int r = 0; r < 4; r++) {
                const unsigned lrow = (unsigned)(wm * 64 + mi * 16 + quad * 4 + r);
                const int rowg = m0 + (int)lrow;
                unsigned k = (((unsigned)accm[mi][ni][r] + 0x800000u) << 8)
                           | (255u - lrow);
                k = (rowg == colg) ? 0u : k;
                key = key > k ? key : k;
            }
        }
        unsigned o = (unsigned)__shfl_xor((int)key, 16, 64);
        key = key > o ? key : o;
        o = (unsigned)__shfl_xor((int)key, 32, 64);
        key = key > o ? key : o;
        if (quad == 0) cmerge[(wn * 64 + ni * 16 + qr) * 2 + wm] = key;
    }
    __syncthreads();

    if (t < TM) {
        unsigned a0 = rmerge[t * 4], a1 = rmerge[t * 4 + 1];
        unsigned a2 = rmerge[t * 4 + 2], a3 = rmerge[t * 4 + 3];
        unsigned k01 = a0 > a1 ? a0 : a1;
        unsigned k23 = a2 > a3 ? a2 : a3;
        unsigned k = k01 > k23 ? k01 : k23;
        // expand to global u64 key: bd32 = dot + 2^31, tie-break smaller col
        unsigned bd32 = (k >> 8) + 0x7F800000u;
        unsigned colg = (unsigned)(n0 + 255) - (k & 255u);
        u64 kk = ((u64)bd32 << 32) | (u64)(0xFFFFFFFFu - colg);
        atomicMax(&best[m0 + t], kk);
    }
    if (t < TN) {
        unsigned c0 = cmerge[t * 2], c1 = cmerge[t * 2 + 1];
        unsigned k = c0 > c1 ? c0 : c1;
        unsigned bd32 = (k >> 8) + 0x7F800000u;
        unsigned rowg = (unsigned)(m0 + 255) - (k & 255u);
        u64 kk = ((u64)bd32 << 32) | (u64)(0xFFFFFFFFu - rowg);
        atomicMax(&best[n0 + t], kk);
    }
}

// ---- kernel 3: exact fp32 distance + fused mean (256-block cheap ticket) ---

__global__ __launch_bounds__(256) void neighbor_reduce(
        const float* __restrict__ in, const float* __restrict__ inv_norm,
        const u64* __restrict__ best, float* __restrict__ acc,
        int* __restrict__ cnt, float* __restrict__ out, int B) {
    const int wave = threadIdx.x >> 6;
    const int lane = threadIdx.x & 63;
    float lsum = 0.f;
    #pragma unroll
    for (int rr = 0; rr < 8; rr++) {
        const int row = blockIdx.x * 32 + wave * 8 + rr;
        u64 k   = best[row];
        int nbr = (int)(0xFFFFFFFFu - (unsigned)(k & 0xFFFFFFFFull));
        float ir  = inv_norm[row];
        float inb = inv_norm[nbr];
        const float4* rp = (const float4*)(in + (size_t)row * D_DIM) + lane * 2;
        const float4* np = (const float4*)(in + (size_t)nbr * D_DIM) + lane * 2;
        float4 r0 = rp[0], r1 = rp[1], q0 = np[0], q1 = np[1];
        float d0 = r0.x*ir - q0.x*inb + 1e-8f, d1 = r0.y*ir - q0.y*inb + 1e-8f;
        float d2 = r0.z*ir - q0.z*inb + 1e-8f, d3 = r0.w*ir - q0.w*inb + 1e-8f;
        float d4 = r1.x*ir - q1.x*inb + 1e-8f, d5 = r1.y*ir - q1.y*inb + 1e-8f;
        float d6 = r1.z*ir - q1.z*inb + 1e-8f, d7 = r1.w*ir - q1.w*inb + 1e-8f;
        float s = d0*d0 + d1*d1 + d2*d2 + d3*d3 + d4*d4 + d5*d5 + d6*d6 + d7*d7;
        #pragma unroll
        for (int m = 1; m <= 32; m <<= 1) s += __shfl_xor(s, m, 64);
        if (lane == 0) lsum += logf(sqrtf(s) + 1e-8f);
    }
    __shared__ float sb[4];
    if (lane == 0) sb[wave] = lsum;
    __syncthreads();
    if (threadIdx.x == 0) {
        float partial = sb[0] + sb[1] + sb[2] + sb[3];
        atomicAdd(acc, partial);
        __threadfence();
        int done = atomicAdd(cnt, 1);
        if (done == gridDim.x - 1) {
            __threadfence();
            float tot = atomicAdd(acc, 0.0f);   // device-scope read of final sum
            out[0] = -tot / (float)B;
        }
    }
}

// ---- launch ----------------------------------------------------------------

extern "C" void kernel_launch(void* const* d_in, const int* in_sizes, int n_in,
                              void* d_out, int out_size, void* d_ws, size_t ws_size,
                              hipStream_t stream) {
    const float* in = (const float*)d_in[0];
    const int B = in_sizes[0] / D_DIM;          // 8192
    const int nblk = 144 * 8;                   // 1152: 144 ranks x 8 XCDs

    char* w = (char*)d_ws;
    unsigned char* xb = (unsigned char*)w;                     // B*D int8
    float* invn = (float*)(w + (size_t)B * D_DIM);
    u64*   best = (u64*)(w + (size_t)B * D_DIM + (size_t)B * 4);
    float* acc  = (float*)(w + (size_t)B * D_DIM + (size_t)B * 4 + (size_t)B * 8);
    int*   cnt  = (int*)(acc + 1);
    float* out  = (float*)d_out;

    normalize_rows<<<B / 4, 256, 0, stream>>>(in, xb, invn, best, acc, cnt);
    gemm_argmax<<<nblk, 512, 0, stream>>>(xb, best);
    neighbor_reduce<<<B / 32, 256, 0, stream>>>(in, invn, best, acc, cnt, out, B);
}